// Round 1
// baseline (435.727 us; speedup 1.0000x reference)
//
#include <hip/hip_runtime.h>
#include <stdint.h>

typedef __attribute__((ext_vector_type(8))) __bf16 bf16x8;
typedef __attribute__((ext_vector_type(4))) float f32x4;

__device__ inline unsigned short f32_to_bf16_rne(float f) {
  union { float f; uint32_t u; } c; c.f = f;
  uint32_t u = c.u;
  uint32_t r = (u + 0x7FFFu + ((u >> 16) & 1u)) >> 16;
  return (unsigned short)r;
}

// ---------- pass 1: x (f32) -> A (bf16 bits) ----------
__global__ __launch_bounds__(256) void convert_x_kernel(const float* __restrict__ X,
                                                        unsigned short* __restrict__ A,
                                                        size_t n) {
  size_t i = (size_t)blockIdx.x * 256 + threadIdx.x;
  size_t stride = (size_t)gridDim.x * 256;
  for (size_t e = i * 4; e < n; e += stride * 4) {
    const float4 v = *reinterpret_cast<const float4*>(X + e);
    ushort4 o;
    o.x = f32_to_bf16_rne(v.x);
    o.y = f32_to_bf16_rne(v.y);
    o.z = f32_to_bf16_rne(v.z);
    o.w = f32_to_bf16_rne(v.w);
    *reinterpret_cast<ushort4*>(A + e) = o;
  }
}

// ---------- pass 2: Bt[n][k] = sign(Km[k][n]) as bf16 (+1/-1 exact) ----------
__global__ __launch_bounds__(256) void sign_transpose_kernel(const float* __restrict__ Km,
                                                             unsigned short* __restrict__ Bt,
                                                             int K, int N) {
  __shared__ unsigned short tile[64][65];
  const int k0 = blockIdx.x * 64;
  const int n0 = blockIdx.y * 64;
  const int t = threadIdx.x;
#pragma unroll
  for (int i = 0; i < 16; ++i) {
    int idx = t + i * 256;
    int kk = idx >> 6, nn = idx & 63;
    float v = Km[(size_t)(k0 + kk) * N + (n0 + nn)];
    tile[kk][nn] = (v >= 0.0f) ? (unsigned short)0x3F80u : (unsigned short)0xBF80u;
  }
  __syncthreads();
#pragma unroll
  for (int i = 0; i < 16; ++i) {
    int idx = t + i * 256;
    int nn = idx >> 6, kk = idx & 63;
    Bt[(size_t)(n0 + nn) * K + (k0 + kk)] = tile[kk][nn];
  }
}

// ---------- pass 3: bf16 MFMA GEMM, m97 structure ----------
// A: [M][K] bf16 row-major; Bt: [N][K] bf16 row-major; C: [M][N] f32.
// 128x128 tile, BK=32, 256 threads = 4 waves in 2x2; each wave does 64x64
// via 4x4 fragments of mfma_f32_16x16x32_bf16.
#define BM 128
#define BN 128
#define BK 32

__global__ __launch_bounds__(256) void gemm_bf16_bt(const unsigned short* __restrict__ A,
                                                    const unsigned short* __restrict__ Bt,
                                                    float* __restrict__ C,
                                                    int M, int N, int K) {
  __shared__ unsigned short As[BM * BK];  // 8 KiB, [row][k] row-major, 64 B/row
  __shared__ unsigned short Bs[BN * BK];  // 8 KiB, [n][k]

  const int nBN = N / BN;
  const int nwg = gridDim.x;
  int bid = (int)blockIdx.x;
  // bijective XCD-aware swizzle (valid since nwg % 8 == 0 for this shape)
  int swz = bid;
  if ((nwg & 7) == 0) {
    int q = nwg >> 3;
    swz = (bid & 7) * q + (bid >> 3);
  }
  const int bm = swz / nBN;
  const int bn = swz % nBN;

  const int tid = threadIdx.x;
  const int wv = tid >> 6;
  const int ln = tid & 63;
  const int lhi = ln >> 4;  // 0..3 -> k-quarter
  const int llo = ln & 15;  // 0..15 -> row/col within fragment
  const int wr = wv >> 1;   // wave row 0..1
  const int wc = wv & 1;    // wave col 0..1

  const size_t a_row0 = (size_t)bm * BM;
  const size_t b_row0 = (size_t)bn * BN;

  f32x4 acc[4][4];
#pragma unroll
  for (int i = 0; i < 4; ++i)
#pragma unroll
    for (int j = 0; j < 4; ++j) acc[i][j] = (f32x4){0.f, 0.f, 0.f, 0.f};

  for (int k0 = 0; k0 < K; k0 += BK) {
    // ---- stage A,B tiles: global -> LDS, 16 B per lane per issue ----
    // LDS dest is wave-uniform base + lane*16 (HW rule); layout is linear
    // row-major [128][32] bf16 (64 B per row), so issue i + wave wv covers
    // bytes [i*4096 + wv*1024, +1024).
#pragma unroll
    for (int i = 0; i < 2; ++i) {
      const int o = i * 4096 + wv * 1024 + ln * 16;  // this lane's dest byte
      const int row = o >> 6;
      const int cb = o & 63;  // byte within row
      const unsigned short* ga = A + (a_row0 + row) * (size_t)K + k0 + (cb >> 1);
      __builtin_amdgcn_global_load_lds(
          (const __attribute__((address_space(1))) void*)ga,
          (__attribute__((address_space(3))) void*)(As + ((i * 4096 + wv * 1024) >> 1)),
          16, 0, 0);
      const unsigned short* gb = Bt + (b_row0 + row) * (size_t)K + k0 + (cb >> 1);
      __builtin_amdgcn_global_load_lds(
          (const __attribute__((address_space(1))) void*)gb,
          (__attribute__((address_space(3))) void*)(Bs + ((i * 4096 + wv * 1024) >> 1)),
          16, 0, 0);
    }
    __syncthreads();  // compiler drains vmcnt(0) before s_barrier

    // ---- fragments: lane holds 8 contiguous k at k = lhi*8 ----
    bf16x8 a[4], b[4];
#pragma unroll
    for (int mi = 0; mi < 4; ++mi)
      a[mi] = *reinterpret_cast<const bf16x8*>(&As[(wr * 64 + mi * 16 + llo) * BK + lhi * 8]);
#pragma unroll
    for (int ni = 0; ni < 4; ++ni)
      b[ni] = *reinterpret_cast<const bf16x8*>(&Bs[(wc * 64 + ni * 16 + llo) * BK + lhi * 8]);

#pragma unroll
    for (int mi = 0; mi < 4; ++mi)
#pragma unroll
      for (int ni = 0; ni < 4; ++ni)
        acc[mi][ni] = __builtin_amdgcn_mfma_f32_16x16x32_bf16(a[mi], b[ni], acc[mi][ni], 0, 0, 0);

    __syncthreads();
  }

  // ---- epilogue: C/D layout col = lane&15, row = (lane>>4)*4 + reg ----
#pragma unroll
  for (int mi = 0; mi < 4; ++mi) {
#pragma unroll
    for (int ni = 0; ni < 4; ++ni) {
      const size_t col = b_row0 + wc * 64 + ni * 16 + llo;
#pragma unroll
      for (int j = 0; j < 4; ++j) {
        const size_t rowg = a_row0 + wr * 64 + mi * 16 + lhi * 4 + j;
        C[rowg * N + col] = acc[mi][ni][j];
      }
    }
  }
}

// ---------- fallback: f32 tiled GEMM (only if ws_size too small) ----------
__global__ __launch_bounds__(256) void gemm_f32_fallback(const float* __restrict__ X,
                                                         const float* __restrict__ Km,
                                                         float* __restrict__ C,
                                                         int M, int N, int K) {
  __shared__ float As[64][16];
  __shared__ float Bs[16][65];
  const int nBN = N / 64;
  const int bm = blockIdx.x / nBN;
  const int bn = blockIdx.x % nBN;
  const int t = threadIdx.x;
  const int tx = t & 15, ty = t >> 4;
  float acc[4][4] = {};
  for (int kb = 0; kb < K; kb += 16) {
#pragma unroll
    for (int i = 0; i < 4; ++i) {
      int e = t + i * 256;
      int r = e >> 4, c = e & 15;
      As[r][c] = X[(size_t)(bm * 64 + r) * K + kb + c];
      int rk = e >> 6, cn = e & 63;
      float v = Km[(size_t)(kb + rk) * N + bn * 64 + cn];
      Bs[rk][cn] = (v >= 0.f) ? 1.f : -1.f;
    }
    __syncthreads();
#pragma unroll
    for (int kk = 0; kk < 16; ++kk) {
      float a[4], b[4];
#pragma unroll
      for (int r = 0; r < 4; ++r) a[r] = As[ty * 4 + r][kk];
#pragma unroll
      for (int c = 0; c < 4; ++c) b[c] = Bs[kk][tx * 4 + c];
#pragma unroll
      for (int r = 0; r < 4; ++r)
#pragma unroll
        for (int c = 0; c < 4; ++c) acc[r][c] += a[r] * b[c];
    }
    __syncthreads();
  }
#pragma unroll
  for (int r = 0; r < 4; ++r)
#pragma unroll
    for (int c = 0; c < 4; ++c)
      C[(size_t)(bm * 64 + ty * 4 + r) * N + bn * 64 + tx * 4 + c] = acc[r][c];
}

extern "C" void kernel_launch(void* const* d_in, const int* in_sizes, int n_in,
                              void* d_out, int out_size, void* d_ws, size_t ws_size,
                              hipStream_t stream) {
  const float* x = (const float*)d_in[0];
  const float* kern = (const float*)d_in[1];
  float* out = (float*)d_out;

  const int K = 4096;  // D_IN
  const int N = 4096;  // UNITS
  const int M = in_sizes[0] / K;  // 8192

  const size_t a_bytes = (size_t)M * K * 2;
  const size_t b_bytes = (size_t)N * K * 2;

  if (ws_size >= a_bytes + b_bytes) {
    unsigned short* A = (unsigned short*)d_ws;
    unsigned short* Bt = (unsigned short*)((char*)d_ws + a_bytes);
    convert_x_kernel<<<2048, 256, 0, stream>>>(x, A, (size_t)M * K);
    sign_transpose_kernel<<<dim3(K / 64, N / 64), 256, 0, stream>>>(kern, Bt, K, N);
    gemm_bf16_bt<<<(M / BM) * (N / BN), 256, 0, stream>>>(A, Bt, out, M, N, K);
  } else {
    gemm_f32_fallback<<<(M / 64) * (N / 64), 256, 0, stream>>>(x, kern, out, M, N, K);
  }
}

// Round 2
// 291.447 us; speedup vs baseline: 1.4951x; 1.4951x over previous
//
#include <hip/hip_runtime.h>
#include <stdint.h>

typedef __attribute__((ext_vector_type(8))) __bf16 bf16x8;
typedef __attribute__((ext_vector_type(4))) float f32x4;

__device__ inline unsigned short f32_to_bf16_rne(float f) {
  union { float f; uint32_t u; } c; c.f = f;
  uint32_t u = c.u;
  uint32_t r = (u + 0x7FFFu + ((u >> 16) & 1u)) >> 16;
  return (unsigned short)r;
}

// ---------- pass 1: x (f32) -> A (bf16 bits) ----------
__global__ __launch_bounds__(256) void convert_x_kernel(const float* __restrict__ X,
                                                        unsigned short* __restrict__ A,
                                                        size_t n) {
  size_t i = (size_t)blockIdx.x * 256 + threadIdx.x;
  size_t stride = (size_t)gridDim.x * 256;
  for (size_t e = i * 4; e < n; e += stride * 4) {
    const float4 v = *reinterpret_cast<const float4*>(X + e);
    ushort4 o;
    o.x = f32_to_bf16_rne(v.x);
    o.y = f32_to_bf16_rne(v.y);
    o.z = f32_to_bf16_rne(v.z);
    o.w = f32_to_bf16_rne(v.w);
    *reinterpret_cast<ushort4*>(A + e) = o;
  }
}

// ---------- pass 2: Bt[n][k] = sign(Km[k][n]) as bf16 (+1/-1 exact) ----------
__global__ __launch_bounds__(256) void sign_transpose_kernel(const float* __restrict__ Km,
                                                             unsigned short* __restrict__ Bt,
                                                             int K, int N) {
  __shared__ unsigned short tile[64][65];
  const int k0 = blockIdx.x * 64;
  const int n0 = blockIdx.y * 64;
  const int t = threadIdx.x;
#pragma unroll
  for (int i = 0; i < 16; ++i) {
    int idx = t + i * 256;
    int kk = idx >> 6, nn = idx & 63;
    float v = Km[(size_t)(k0 + kk) * N + (n0 + nn)];
    tile[kk][nn] = (v >= 0.0f) ? (unsigned short)0x3F80u : (unsigned short)0xBF80u;
  }
  __syncthreads();
#pragma unroll
  for (int i = 0; i < 16; ++i) {
    int idx = t + i * 256;
    int nn = idx >> 6, kk = idx & 63;
    Bt[(size_t)(n0 + nn) * K + (k0 + kk)] = tile[kk][nn];
  }
}

// ---------- pass 3: 256x256-tile bf16 MFMA GEMM, deep-pipelined ----------
// A: [M][K] bf16 row-major; Bt: [N][K] bf16 row-major; C: [M][N] f32.
// 512 threads = 8 waves in 2(M)x4(N); wave output 128x64 via 8x4 16x16 frags.
// BK=32 K-tiles in a 4-deep circular LDS buffer (4 x 32 KiB = 128 KiB).
// Schedule per iter t (consume buf[t&3], stage tile t+3 into buf[(t+3)&3]):
//   phase0: ds_read 4 B-frags + 4 A-frags | stage A(t+3) | bar | lgkm0 | 16 MFMA | bar
//   phase1: ds_read 4 A-frags (B in regs) | stage B(t+3) | bar | lgkm0 | 16 MFMA | vmcnt(8) | bar
// vmcnt(8) = 2 tiles x 4 gl_lds in flight (counted, never 0 in loop).
// Race-free: buf[(t+3)&3] was consumed at iter t-1; all its ds_reads are
// lgkm-confirmed before iter t-1's final barrier, which precedes iter t's
// stage issues in every wave. Tail iters re-stage tile NT-1 (identical
// bytes -> benign) to keep vmcnt immediates uniform.
// T2 swizzle: row = 64 B = 4 slots of 16 B; slot ^= (row>>1)&3 -> 2 lanes per
// bank-quad per 16-lane group (free 2-way). gl_lds dest stays linear; the
// GLOBAL source k-chunk is pre-swizzled by the same involution (rule 21).

__device__ __forceinline__ void stage_mat(const unsigned short* __restrict__ G,
                                          size_t grow0, int K, int k0,
                                          unsigned short* lds_wave_base,  // wave-uniform
                                          int tid) {
#pragma unroll
  for (int i = 0; i < 2; ++i) {
    const int row = i * 128 + (tid >> 2);                 // 0..255
    const int srcslot = (tid & 3) ^ ((row >> 1) & 3);     // pre-swizzled source
    const unsigned short* ga = G + (grow0 + row) * (size_t)K + k0 + srcslot * 8;
    __builtin_amdgcn_global_load_lds(
        (const __attribute__((address_space(1))) void*)ga,
        (__attribute__((address_space(3))) void*)(lds_wave_base + i * 4096),
        16, 0, 0);
  }
}

__global__ __launch_bounds__(512, 2) void gemm_bf16_256(const unsigned short* __restrict__ A,
                                                        const unsigned short* __restrict__ Bt,
                                                        float* __restrict__ C,
                                                        int M, int N, int K) {
  __shared__ unsigned short lds[4 * 16384];  // 128 KiB; per buf: A[256][32] then B[256][32]

  const int nBN = N >> 8;
  const int nwg = gridDim.x;
  const int bid = blockIdx.x;
  int swz = bid;
  if ((nwg & 7) == 0) {  // bijective XCD swizzle
    const int q = nwg >> 3;
    swz = (bid & 7) * q + (bid >> 3);
  }
  const size_t a_row0 = (size_t)(swz / nBN) * 256;
  const size_t b_row0 = (size_t)(swz % nBN) * 256;

  const int tid = threadIdx.x;
  const int wv = tid >> 6, ln = tid & 63;
  const int llo = ln & 15, lhi = ln >> 4;
  const int wr = wv >> 2, wc = wv & 3;
  const int sA = lhi ^ ((llo >> 1) & 3);  // swizzled 16B-slot for ds_read

  // per-lane ds_read bases (shorts, relative to buf start)
  const int aoff = (wr * 128 + llo) * 32 + sA * 8;
  const int boff = 8192 + (wc * 64 + llo) * 32 + sA * 8;

  const int NTt = K >> 5;  // 128 K-tiles

  f32x4 acc[8][4];
#pragma unroll
  for (int i = 0; i < 8; ++i)
#pragma unroll
    for (int j = 0; j < 4; ++j) acc[i][j] = (f32x4){0.f, 0.f, 0.f, 0.f};

  // ---- prologue: stage tiles 0,1,2 (12 gl_lds/wave), confirm tile 0 ----
#pragma unroll
  for (int tt = 0; tt < 3; ++tt) {
    stage_mat(A, a_row0, K, tt * 32, &lds[tt * 16384 + wv * 512], tid);
    stage_mat(Bt, b_row0, K, tt * 32, &lds[tt * 16384 + 8192 + wv * 512], tid);
  }
  asm volatile("s_waitcnt vmcnt(8)\n" ::: "memory");
  __builtin_amdgcn_s_barrier();

  // ---- main loop ----
  for (int t = 0; t < NTt; ++t) {
    const int cb = (t & 3) * 16384;
    const int ts = (t + 3 < NTt) ? (t + 3) : (NTt - 1);
    const int tb = (ts & 3) * 16384;

    bf16x8 bfr[4], afr[4];
    // phase 0: B-frags (held across both phases) + A quadrant 0
#pragma unroll
    for (int ni = 0; ni < 4; ++ni)
      bfr[ni] = *reinterpret_cast<const bf16x8*>(&lds[cb + boff + ni * 512]);
#pragma unroll
    for (int mi = 0; mi < 4; ++mi)
      afr[mi] = *reinterpret_cast<const bf16x8*>(&lds[cb + aoff + mi * 512]);
    stage_mat(A, a_row0, K, ts * 32, &lds[tb + wv * 512], tid);
    __builtin_amdgcn_s_barrier();
    asm volatile("s_waitcnt lgkmcnt(0)\n" ::: "memory");
    __builtin_amdgcn_sched_barrier(0);
    __builtin_amdgcn_s_setprio(1);
#pragma unroll
    for (int mi = 0; mi < 4; ++mi)
#pragma unroll
      for (int ni = 0; ni < 4; ++ni)
        acc[mi][ni] = __builtin_amdgcn_mfma_f32_16x16x32_bf16(afr[mi], bfr[ni], acc[mi][ni], 0, 0, 0);
    __builtin_amdgcn_s_setprio(0);
    __builtin_amdgcn_s_barrier();

    // phase 1: A quadrant 1 (B reused from regs)
#pragma unroll
    for (int mi = 0; mi < 4; ++mi)
      afr[mi] = *reinterpret_cast<const bf16x8*>(&lds[cb + aoff + 2048 + mi * 512]);
    stage_mat(Bt, b_row0, K, ts * 32, &lds[tb + 8192 + wv * 512], tid);
    __builtin_amdgcn_s_barrier();
    asm volatile("s_waitcnt lgkmcnt(0)\n" ::: "memory");
    __builtin_amdgcn_sched_barrier(0);
    __builtin_amdgcn_s_setprio(1);
#pragma unroll
    for (int mi = 0; mi < 4; ++mi)
#pragma unroll
      for (int ni = 0; ni < 4; ++ni)
        acc[4 + mi][ni] = __builtin_amdgcn_mfma_f32_16x16x32_bf16(afr[mi], bfr[ni], acc[4 + mi][ni], 0, 0, 0);
    __builtin_amdgcn_s_setprio(0);
    asm volatile("s_waitcnt vmcnt(8)\n" ::: "memory");  // tile t+1 landed; t+2,t+3 in flight
    __builtin_amdgcn_s_barrier();
  }

  // ---- epilogue: C/D layout col = lane&15, row = (lane>>4)*4 + reg ----
#pragma unroll
  for (int mi = 0; mi < 8; ++mi) {
#pragma unroll
    for (int ni = 0; ni < 4; ++ni) {
      const size_t col = b_row0 + wc * 64 + ni * 16 + llo;
      const size_t rbase = a_row0 + wr * 128 + mi * 16 + lhi * 4;
#pragma unroll
      for (int j = 0; j < 4; ++j)
        C[(rbase + j) * (size_t)N + col] = acc[mi][ni][j];
    }
  }
}

// ---------- fallback: f32 tiled GEMM (only if ws_size too small) ----------
__global__ __launch_bounds__(256) void gemm_f32_fallback(const float* __restrict__ X,
                                                         const float* __restrict__ Km,
                                                         float* __restrict__ C,
                                                         int M, int N, int K) {
  __shared__ float As[64][16];
  __shared__ float Bs[16][65];
  const int nBN = N / 64;
  const int bm = blockIdx.x / nBN;
  const int bn = blockIdx.x % nBN;
  const int t = threadIdx.x;
  const int tx = t & 15, ty = t >> 4;
  float acc[4][4] = {};
  for (int kb = 0; kb < K; kb += 16) {
#pragma unroll
    for (int i = 0; i < 4; ++i) {
      int e = t + i * 256;
      int r = e >> 4, c = e & 15;
      As[r][c] = X[(size_t)(bm * 64 + r) * K + kb + c];
      int rk = e >> 6, cn = e & 63;
      float v = Km[(size_t)(kb + rk) * N + bn * 64 + cn];
      Bs[rk][cn] = (v >= 0.f) ? 1.f : -1.f;
    }
    __syncthreads();
#pragma unroll
    for (int kk = 0; kk < 16; ++kk) {
      float a[4], b[4];
#pragma unroll
      for (int r = 0; r < 4; ++r) a[r] = As[ty * 4 + r][kk];
#pragma unroll
      for (int c = 0; c < 4; ++c) b[c] = Bs[kk][tx * 4 + c];
#pragma unroll
      for (int r = 0; r < 4; ++r)
#pragma unroll
        for (int c = 0; c < 4; ++c) acc[r][c] += a[r] * b[c];
    }
    __syncthreads();
  }
#pragma unroll
  for (int r = 0; r < 4; ++r)
#pragma unroll
    for (int c = 0; c < 4; ++c)
      C[(size_t)(bm * 64 + ty * 4 + r) * N + bn * 64 + tx * 4 + c] = acc[r][c];
}

extern "C" void kernel_launch(void* const* d_in, const int* in_sizes, int n_in,
                              void* d_out, int out_size, void* d_ws, size_t ws_size,
                              hipStream_t stream) {
  const float* x = (const float*)d_in[0];
  const float* kern = (const float*)d_in[1];
  float* out = (float*)d_out;

  const int K = 4096;             // D_IN
  const int N = 4096;             // UNITS
  const int M = in_sizes[0] / K;  // 8192

  const size_t a_bytes = (size_t)M * K * 2;
  const size_t b_bytes = (size_t)N * K * 2;

  if (ws_size >= a_bytes + b_bytes && (M % 256) == 0 && (N % 256) == 0 && (K % 32) == 0) {
    unsigned short* A = (unsigned short*)d_ws;
    unsigned short* Bt = (unsigned short*)((char*)d_ws + a_bytes);
    convert_x_kernel<<<2048, 256, 0, stream>>>(x, A, (size_t)M * K);
    sign_transpose_kernel<<<dim3(K / 64, N / 64), 256, 0, stream>>>(kern, Bt, K, N);
    gemm_bf16_256<<<(M / 256) * (N / 256), 512, 0, stream>>>(A, Bt, out, M, N, K);
  } else {
    gemm_f32_fallback<<<(M / 64) * (N / 64), 256, 0, stream>>>(x, kern, out, M, N, K);
  }
}

// Round 3
// 280.064 us; speedup vs baseline: 1.5558x; 1.0406x over previous
//
#include <hip/hip_runtime.h>
#include <stdint.h>

typedef __attribute__((ext_vector_type(8))) __bf16 bf16x8;
typedef __attribute__((ext_vector_type(4))) float f32x4;

__device__ inline unsigned short f32_to_bf16_rne(float f) {
  union { float f; uint32_t u; } c; c.f = f;
  uint32_t u = c.u;
  uint32_t r = (u + 0x7FFFu + ((u >> 16) & 1u)) >> 16;
  return (unsigned short)r;
}

// ---------- pass 1: x (f32) -> A (bf16 bits) ----------
__global__ __launch_bounds__(256) void convert_x_kernel(const float* __restrict__ X,
                                                        unsigned short* __restrict__ A,
                                                        size_t n) {
  size_t i = (size_t)blockIdx.x * 256 + threadIdx.x;
  size_t stride = (size_t)gridDim.x * 256;
  for (size_t e = i * 4; e < n; e += stride * 4) {
    const float4 v = *reinterpret_cast<const float4*>(X + e);
    ushort4 o;
    o.x = f32_to_bf16_rne(v.x);
    o.y = f32_to_bf16_rne(v.y);
    o.z = f32_to_bf16_rne(v.z);
    o.w = f32_to_bf16_rne(v.w);
    *reinterpret_cast<ushort4*>(A + e) = o;
  }
}

// ---------- pass 2: Bt[n][k] = sign(Km[k][n]) as bf16 (+1/-1 exact) ----------
__global__ __launch_bounds__(256) void sign_transpose_kernel(const float* __restrict__ Km,
                                                             unsigned short* __restrict__ Bt,
                                                             int K, int N) {
  __shared__ unsigned short tile[64][65];
  const int k0 = blockIdx.x * 64;
  const int n0 = blockIdx.y * 64;
  const int t = threadIdx.x;
#pragma unroll
  for (int i = 0; i < 16; ++i) {
    int idx = t + i * 256;
    int kk = idx >> 6, nn = idx & 63;
    float v = Km[(size_t)(k0 + kk) * N + (n0 + nn)];
    tile[kk][nn] = (v >= 0.0f) ? (unsigned short)0x3F80u : (unsigned short)0xBF80u;
  }
  __syncthreads();
#pragma unroll
  for (int i = 0; i < 16; ++i) {
    int idx = t + i * 256;
    int nn = idx >> 6, kk = idx & 63;
    Bt[(size_t)(n0 + nn) * K + (k0 + kk)] = tile[kk][nn];
  }
}

// ---------- pass 3: 256x256-tile bf16 MFMA GEMM, deep-pipelined ----------
// A: [M][K] bf16 row-major; Bt: [N][K] bf16 row-major; C: [M][N] f32.
// 512 threads = 8 waves in 2(M)x4(N); wave output 128x64 via 8x4 16x16 frags.
// BK=32 K-tiles in a 4-deep circular LDS buffer (4 x 32 KiB = 128 KiB).
//
// ONE barrier + ONE counted vmcnt per iteration. Safety proof:
//  - Between barrier B(t-1) and B(t), every wave executes iteration t only.
//  - Write-after-read: iter t stages into buf[(t+3)&3] == buf[(t-1)&3], whose
//    reads (iter t-1) were all lgkm-drained before B(t-1) (compiler inserts
//    lgkm waits before the final MFMA cluster, which precedes the barrier).
//  - Read-after-write: vmcnt(8) before B(j) confirms each wave's own stages
//    through iter j-2, i.e. tile j+1. So at B(t-1), tiles <= t are landed
//    from EVERY wave -> iter t's ds_reads of tile t are safe.
//  - Tail iters re-stage tile NT-1 (identical bytes -> benign) to keep the
//    vmcnt immediate uniform.
// T2 swizzle: row = 64 B = 4 slots of 16 B; slot ^= (row>>1)&3 (2-way free).
// gl_lds dest stays linear; the GLOBAL source k-chunk is pre-swizzled by the
// same involution (rule 21). Verified r2: SQ_LDS_BANK_CONFLICT == 0.

__device__ __forceinline__ void stage_mat(const unsigned short* __restrict__ G,
                                          size_t grow0, int K, int k0,
                                          unsigned short* lds_wave_base,  // wave-uniform
                                          int tid) {
#pragma unroll
  for (int i = 0; i < 2; ++i) {
    const int row = i * 128 + (tid >> 2);                 // 0..255
    const int srcslot = (tid & 3) ^ ((row >> 1) & 3);     // pre-swizzled source
    const unsigned short* ga = G + (grow0 + row) * (size_t)K + k0 + srcslot * 8;
    __builtin_amdgcn_global_load_lds(
        (const __attribute__((address_space(1))) void*)ga,
        (__attribute__((address_space(3))) void*)(lds_wave_base + i * 4096),
        16, 0, 0);
  }
}

__global__ __launch_bounds__(512, 2) void gemm_bf16_256(const unsigned short* __restrict__ A,
                                                        const unsigned short* __restrict__ Bt,
                                                        float* __restrict__ C,
                                                        int M, int N, int K) {
  __shared__ unsigned short lds[4 * 16384];  // 128 KiB; per buf: A[256][32] then B[256][32]

  const int nBN = N >> 8;
  const int nwg = gridDim.x;
  const int bid = blockIdx.x;
  int swz = bid;
  if ((nwg & 7) == 0) {  // bijective XCD swizzle
    const int q = nwg >> 3;
    swz = (bid & 7) * q + (bid >> 3);
  }
  const size_t a_row0 = (size_t)(swz / nBN) * 256;
  const size_t b_row0 = (size_t)(swz % nBN) * 256;

  const int tid = threadIdx.x;
  const int wv = tid >> 6, ln = tid & 63;
  const int llo = ln & 15, lhi = ln >> 4;
  const int wr = wv >> 2, wc = wv & 3;
  const int sA = lhi ^ ((llo >> 1) & 3);  // swizzled 16B-slot for ds_read

  // per-lane ds_read bases (shorts, relative to buf start)
  const int aoff = (wr * 128 + llo) * 32 + sA * 8;
  const int boff = 8192 + (wc * 64 + llo) * 32 + sA * 8;

  const int NTt = K >> 5;  // 128 K-tiles

  f32x4 acc[8][4];
#pragma unroll
  for (int i = 0; i < 8; ++i)
#pragma unroll
    for (int j = 0; j < 4; ++j) acc[i][j] = (f32x4){0.f, 0.f, 0.f, 0.f};

  // ---- prologue: stage tiles 0,1,2 (12 gl_lds/wave), confirm tile 0 ----
#pragma unroll
  for (int tt = 0; tt < 3; ++tt) {
    stage_mat(A, a_row0, K, tt * 32, &lds[tt * 16384 + wv * 512], tid);
    stage_mat(Bt, b_row0, K, tt * 32, &lds[tt * 16384 + 8192 + wv * 512], tid);
  }
  asm volatile("s_waitcnt vmcnt(8)\n" ::: "memory");
  __builtin_amdgcn_s_barrier();

  // ---- main loop: 1 barrier / iter ----
  for (int t = 0; t < NTt; ++t) {
    const int cb = (t & 3) * 16384;
    const int ts = (t + 3 < NTt) ? (t + 3) : (NTt - 1);
    const int tb = (ts & 3) * 16384;

    bf16x8 bfr[4], af0[4], af1[4];
    // issue ALL frag reads (12 x ds_read_b128) + ALL stages (4 x gl_lds)
#pragma unroll
    for (int ni = 0; ni < 4; ++ni)
      bfr[ni] = *reinterpret_cast<const bf16x8*>(&lds[cb + boff + ni * 512]);
#pragma unroll
    for (int mi = 0; mi < 4; ++mi)
      af0[mi] = *reinterpret_cast<const bf16x8*>(&lds[cb + aoff + mi * 512]);
#pragma unroll
    for (int mi = 0; mi < 4; ++mi)
      af1[mi] = *reinterpret_cast<const bf16x8*>(&lds[cb + aoff + 2048 + mi * 512]);
    stage_mat(A, a_row0, K, ts * 32, &lds[tb + wv * 512], tid);
    stage_mat(Bt, b_row0, K, ts * 32, &lds[tb + 8192 + wv * 512], tid);
    __builtin_amdgcn_sched_barrier(0);  // pin: all issues precede MFMA clusters

    // MFMA cluster 0 (compiler inserts counted lgkm wait for bfr/af0 only)
    __builtin_amdgcn_s_setprio(1);
#pragma unroll
    for (int mi = 0; mi < 4; ++mi)
#pragma unroll
      for (int ni = 0; ni < 4; ++ni)
        acc[mi][ni] = __builtin_amdgcn_mfma_f32_16x16x32_bf16(af0[mi], bfr[ni], acc[mi][ni], 0, 0, 0);
    __builtin_amdgcn_s_setprio(0);
    __builtin_amdgcn_sched_barrier(0);

    // MFMA cluster 1 (af1 drained here by compiler's lgkm wait)
    __builtin_amdgcn_s_setprio(1);
#pragma unroll
    for (int mi = 0; mi < 4; ++mi)
#pragma unroll
      for (int ni = 0; ni < 4; ++ni)
        acc[4 + mi][ni] = __builtin_amdgcn_mfma_f32_16x16x32_bf16(af1[mi], bfr[ni], acc[4 + mi][ni], 0, 0, 0);
    __builtin_amdgcn_s_setprio(0);

    asm volatile("s_waitcnt vmcnt(8)\n" ::: "memory");  // tile t+1 fully landed
    __builtin_amdgcn_s_barrier();
  }

  // ---- epilogue: C/D layout col = lane&15, row = (lane>>4)*4 + reg ----
#pragma unroll
  for (int mi = 0; mi < 8; ++mi) {
#pragma unroll
    for (int ni = 0; ni < 4; ++ni) {
      const size_t col = b_row0 + wc * 64 + ni * 16 + llo;
      const size_t rbase = a_row0 + wr * 128 + mi * 16 + lhi * 4;
#pragma unroll
      for (int j = 0; j < 4; ++j)
        C[(rbase + j) * (size_t)N + col] = acc[mi][ni][j];
    }
  }
}

// ---------- fallback: f32 tiled GEMM (only if ws_size too small) ----------
__global__ __launch_bounds__(256) void gemm_f32_fallback(const float* __restrict__ X,
                                                         const float* __restrict__ Km,
                                                         float* __restrict__ C,
                                                         int M, int N, int K) {
  __shared__ float As[64][16];
  __shared__ float Bs[16][65];
  const int nBN = N / 64;
  const int bm = blockIdx.x / nBN;
  const int bn = blockIdx.x % nBN;
  const int t = threadIdx.x;
  const int tx = t & 15, ty = t >> 4;
  float acc[4][4] = {};
  for (int kb = 0; kb < K; kb += 16) {
#pragma unroll
    for (int i = 0; i < 4; ++i) {
      int e = t + i * 256;
      int r = e >> 4, c = e & 15;
      As[r][c] = X[(size_t)(bm * 64 + r) * K + kb + c];
      int rk = e >> 6, cn = e & 63;
      float v = Km[(size_t)(kb + rk) * N + bn * 64 + cn];
      Bs[rk][cn] = (v >= 0.f) ? 1.f : -1.f;
    }
    __syncthreads();
#pragma unroll
    for (int kk = 0; kk < 16; ++kk) {
      float a[4], b[4];
#pragma unroll
      for (int r = 0; r < 4; ++r) a[r] = As[ty * 4 + r][kk];
#pragma unroll
      for (int c = 0; c < 4; ++c) b[c] = Bs[kk][tx * 4 + c];
#pragma unroll
      for (int r = 0; r < 4; ++r)
#pragma unroll
        for (int c = 0; c < 4; ++c) acc[r][c] += a[r] * b[c];
    }
    __syncthreads();
  }
#pragma unroll
  for (int r = 0; r < 4; ++r)
#pragma unroll
    for (int c = 0; c < 4; ++c)
      C[(size_t)(bm * 64 + ty * 4 + r) * N + bn * 64 + tx * 4 + c] = acc[r][c];
}

extern "C" void kernel_launch(void* const* d_in, const int* in_sizes, int n_in,
                              void* d_out, int out_size, void* d_ws, size_t ws_size,
                              hipStream_t stream) {
  const float* x = (const float*)d_in[0];
  const float* kern = (const float*)d_in[1];
  float* out = (float*)d_out;

  const int K = 4096;             // D_IN
  const int N = 4096;             // UNITS
  const int M = in_sizes[0] / K;  // 8192

  const size_t a_bytes = (size_t)M * K * 2;
  const size_t b_bytes = (size_t)N * K * 2;

  if (ws_size >= a_bytes + b_bytes && (M % 256) == 0 && (N % 256) == 0 && (K % 128) == 0) {
    unsigned short* A = (unsigned short*)d_ws;
    unsigned short* Bt = (unsigned short*)((char*)d_ws + a_bytes);
    convert_x_kernel<<<2048, 256, 0, stream>>>(x, A, (size_t)M * K);
    sign_transpose_kernel<<<dim3(K / 64, N / 64), 256, 0, stream>>>(kern, Bt, K, N);
    gemm_bf16_256<<<(M / 256) * (N / 256), 512, 0, stream>>>(A, Bt, out, M, N, K);
  } else {
    gemm_f32_fallback<<<(M / 64) * (N / 64), 256, 0, stream>>>(x, kern, out, M, N, K);
  }
}

// Round 4
// 266.360 us; speedup vs baseline: 1.6359x; 1.0514x over previous
//
#include <hip/hip_runtime.h>
#include <stdint.h>

typedef __attribute__((ext_vector_type(8))) __bf16 bf16x8;
typedef __attribute__((ext_vector_type(4))) float f32x4;

__device__ inline unsigned short f32_to_bf16_rne(float f) {
  union { float f; uint32_t u; } c; c.f = f;
  uint32_t u = c.u;
  uint32_t r = (u + 0x7FFFu + ((u >> 16) & 1u)) >> 16;
  return (unsigned short)r;
}

// ---------- pass 1: x (f32) -> A (bf16 bits) ----------
__global__ __launch_bounds__(256) void convert_x_kernel(const float* __restrict__ X,
                                                        unsigned short* __restrict__ A,
                                                        size_t n) {
  size_t i = (size_t)blockIdx.x * 256 + threadIdx.x;
  size_t stride = (size_t)gridDim.x * 256;
  for (size_t e = i * 4; e < n; e += stride * 4) {
    const float4 v = *reinterpret_cast<const float4*>(X + e);
    ushort4 o;
    o.x = f32_to_bf16_rne(v.x);
    o.y = f32_to_bf16_rne(v.y);
    o.z = f32_to_bf16_rne(v.z);
    o.w = f32_to_bf16_rne(v.w);
    *reinterpret_cast<ushort4*>(A + e) = o;
  }
}

// ---------- pass 2: Bt[n][k] = sign(Km[k][n]) as bf16 (+1/-1 exact) ----------
__global__ __launch_bounds__(256) void sign_transpose_kernel(const float* __restrict__ Km,
                                                             unsigned short* __restrict__ Bt,
                                                             int K, int N) {
  __shared__ unsigned short tile[64][65];
  const int k0 = blockIdx.x * 64;
  const int n0 = blockIdx.y * 64;
  const int t = threadIdx.x;
#pragma unroll
  for (int i = 0; i < 16; ++i) {
    int idx = t + i * 256;
    int kk = idx >> 6, nn = idx & 63;
    float v = Km[(size_t)(k0 + kk) * N + (n0 + nn)];
    tile[kk][nn] = (v >= 0.0f) ? (unsigned short)0x3F80u : (unsigned short)0xBF80u;
  }
  __syncthreads();
#pragma unroll
  for (int i = 0; i < 16; ++i) {
    int idx = t + i * 256;
    int nn = idx >> 6, kk = idx & 63;
    Bt[(size_t)(n0 + nn) * K + (k0 + kk)] = tile[kk][nn];
  }
}

// ---------- pass 3: 256x256-tile bf16 MFMA GEMM, reg-double-buffered ----------
// A: [M][K] bf16 row-major; Bt: [N][K] bf16 row-major; C: [M][N] f32.
// 512 threads = 8 waves in 2(M)x4(N); wave output 128x64 via 8x4 16x16 frags.
// BK=32 K-tiles in a 4-deep circular LDS buffer (4 x 32 KiB = 128 KiB).
//
// SOFTWARE-PIPELINED READS: cluster-0 operands (bfr,af0) for iter t are read
// from LDS during iter t-1 (phase 1), so cluster 0 issues with ZERO lgkm wait
// right after the barrier. af1 reads overlap cluster 0; next-iter reads
// overlap cluster 1. One barrier + one counted vmcnt(4) per iter.
//
// Safety proof (per-wave vmcnt + barrier => block-wide visibility):
//  INVARIANT entering iter t (just after barrier B(t-1)): every wave has
//  executed s_waitcnt vmcnt(4) before B(t-1) with stages issued up to tile
//  t+2 => tiles <= t+1 are LANDED from all waves.
//   - iter t phase-0 reads tile t      (<= t+1, safe)
//   - iter t phase-1 reads tile t+1    (== t+1, safe)
//  Prologue establishes it for t=0: 12 stage-issues (tiles 0,1,2), then
//  vmcnt(4) => tiles 0,1 landed, then barrier.
//  Induction: end of iter t issues stages for tile t+3 => issued <= t+3;
//  vmcnt(4) => confirmed <= t+2 => invariant holds entering t+1.
//  Write-after-read: iter t stages into buf[(t+3)&3] == buf[(t-1)&3]. All
//  reads of tile t-1 (its af1 reads in iter t-1 phase 0; its bfr/af0
//  prefetch reads in iter t-2 phase 1) are lgkm-completed before their
//  consuming MFMA clusters, which precede B(t-1) < iter-t stage issues.
//  Tail: ts clamps to NT-1 (re-stages identical bytes, benign); nb clamps
//  to cb at t=NT-1 (redundant read of a landed tile, benign).
// T2 swizzle: row = 64 B = 4 slots of 16 B; slot ^= (row>>1)&3 (2-way free).
// gl_lds dest stays linear; the GLOBAL source k-chunk is pre-swizzled by the
// same involution (rule 21). Verified r2/r3: SQ_LDS_BANK_CONFLICT == 0.

__device__ __forceinline__ void stage_mat(const unsigned short* __restrict__ G,
                                          size_t grow0, int K, int k0,
                                          unsigned short* lds_wave_base,  // wave-uniform
                                          int tid) {
#pragma unroll
  for (int i = 0; i < 2; ++i) {
    const int row = i * 128 + (tid >> 2);                 // 0..255
    const int srcslot = (tid & 3) ^ ((row >> 1) & 3);     // pre-swizzled source
    const unsigned short* ga = G + (grow0 + row) * (size_t)K + k0 + srcslot * 8;
    __builtin_amdgcn_global_load_lds(
        (const __attribute__((address_space(1))) void*)ga,
        (__attribute__((address_space(3))) void*)(lds_wave_base + i * 4096),
        16, 0, 0);
  }
}

// One pipelined iteration. AFC/BFC: current cluster-0 operands (already in
// regs). AFN/BFN: written with next iteration's cluster-0 operands.
#define GEMM_ITER(T, AFC, BFC, AFN, BFN)                                              \
  {                                                                                   \
    const int cb = ((T) & 3) * 16384;                                                 \
    const int ts = ((T) + 3 < NTt) ? ((T) + 3) : (NTt - 1);                           \
    const int tb = (ts & 3) * 16384;                                                  \
    bf16x8 af1[4];                                                                    \
    _Pragma("unroll")                                                                 \
    for (int mi = 0; mi < 4; ++mi)                                                    \
      af1[mi] = *reinterpret_cast<const bf16x8*>(&lds[cb + aoff + 2048 + mi * 512]);  \
    stage_mat(A, a_row0, K, ts * 32, &lds[tb + wv * 512], tid);                       \
    __builtin_amdgcn_sched_barrier(0);                                                \
    __builtin_amdgcn_s_setprio(1);                                                    \
    _Pragma("unroll")                                                                 \
    for (int mi = 0; mi < 4; ++mi)                                                    \
      _Pragma("unroll")                                                               \
      for (int ni = 0; ni < 4; ++ni)                                                  \
        acc[mi][ni] =                                                                 \
            __builtin_amdgcn_mfma_f32_16x16x32_bf16(AFC[mi], BFC[ni], acc[mi][ni], 0, 0, 0); \
    __builtin_amdgcn_s_setprio(0);                                                    \
    __builtin_amdgcn_sched_barrier(0);                                                \
    const int nb = ((T) + 1 < NTt) ? ((((T) + 1) & 3) * 16384) : cb;                  \
    _Pragma("unroll")                                                                 \
    for (int ni = 0; ni < 4; ++ni)                                                    \
      BFN[ni] = *reinterpret_cast<const bf16x8*>(&lds[nb + boff + ni * 512]);         \
    _Pragma("unroll")                                                                 \
    for (int mi = 0; mi < 4; ++mi)                                                    \
      AFN[mi] = *reinterpret_cast<const bf16x8*>(&lds[nb + aoff + mi * 512]);         \
    stage_mat(Bt, b_row0, K, ts * 32, &lds[tb + 8192 + wv * 512], tid);               \
    __builtin_amdgcn_sched_barrier(0);                                                \
    __builtin_amdgcn_s_setprio(1);                                                    \
    _Pragma("unroll")                                                                 \
    for (int mi = 0; mi < 4; ++mi)                                                    \
      _Pragma("unroll")                                                               \
      for (int ni = 0; ni < 4; ++ni)                                                  \
        acc[4 + mi][ni] =                                                             \
            __builtin_amdgcn_mfma_f32_16x16x32_bf16(af1[mi], BFC[ni], acc[4 + mi][ni], 0, 0, 0); \
    __builtin_amdgcn_s_setprio(0);                                                    \
    asm volatile("s_waitcnt vmcnt(4)\n" ::: "memory");                                \
    __builtin_amdgcn_s_barrier();                                                     \
  }

__global__ __launch_bounds__(512, 2) void gemm_bf16_256(const unsigned short* __restrict__ A,
                                                        const unsigned short* __restrict__ Bt,
                                                        float* __restrict__ C,
                                                        int M, int N, int K) {
  __shared__ unsigned short lds[4 * 16384];  // 128 KiB; per buf: A[256][32] then B[256][32]

  const int nBN = N >> 8;
  const int nwg = gridDim.x;
  const int bid = blockIdx.x;
  int swz = bid;
  if ((nwg & 7) == 0) {  // bijective XCD swizzle
    const int q = nwg >> 3;
    swz = (bid & 7) * q + (bid >> 3);
  }
  const size_t a_row0 = (size_t)(swz / nBN) * 256;
  const size_t b_row0 = (size_t)(swz % nBN) * 256;

  const int tid = threadIdx.x;
  const int wv = tid >> 6, ln = tid & 63;
  const int llo = ln & 15, lhi = ln >> 4;
  const int wr = wv >> 2, wc = wv & 3;
  const int sA = lhi ^ ((llo >> 1) & 3);  // swizzled 16B-slot for ds_read

  // per-lane ds_read bases (shorts, relative to buf start)
  const int aoff = (wr * 128 + llo) * 32 + sA * 8;
  const int boff = 8192 + (wc * 64 + llo) * 32 + sA * 8;

  const int NTt = K >> 5;  // 128 K-tiles (even; launch guards K%128==0)

  f32x4 acc[8][4];
#pragma unroll
  for (int i = 0; i < 8; ++i)
#pragma unroll
    for (int j = 0; j < 4; ++j) acc[i][j] = (f32x4){0.f, 0.f, 0.f, 0.f};

  // ---- prologue: stage tiles 0,1,2; confirm tiles 0 AND 1; preload t=0 ----
#pragma unroll
  for (int tt = 0; tt < 3; ++tt) {
    stage_mat(A, a_row0, K, tt * 32, &lds[tt * 16384 + wv * 512], tid);
    stage_mat(Bt, b_row0, K, tt * 32, &lds[tt * 16384 + 8192 + wv * 512], tid);
  }
  asm volatile("s_waitcnt vmcnt(4)\n" ::: "memory");
  __builtin_amdgcn_s_barrier();

  bf16x8 af0_a[4], bfr_a[4], af0_b[4], bfr_b[4];
#pragma unroll
  for (int ni = 0; ni < 4; ++ni)
    bfr_a[ni] = *reinterpret_cast<const bf16x8*>(&lds[boff + ni * 512]);
#pragma unroll
  for (int mi = 0; mi < 4; ++mi)
    af0_a[mi] = *reinterpret_cast<const bf16x8*>(&lds[aoff + mi * 512]);

  // ---- main loop: 2x unrolled, ping-pong register sets ----
  for (int t = 0; t < NTt; t += 2) {
    GEMM_ITER(t, af0_a, bfr_a, af0_b, bfr_b)
    GEMM_ITER(t + 1, af0_b, bfr_b, af0_a, bfr_a)
  }

  // ---- epilogue: C/D layout col = lane&15, row = (lane>>4)*4 + reg ----
#pragma unroll
  for (int mi = 0; mi < 8; ++mi) {
#pragma unroll
    for (int ni = 0; ni < 4; ++ni) {
      const size_t col = b_row0 + wc * 64 + ni * 16 + llo;
      const size_t rbase = a_row0 + wr * 128 + mi * 16 + lhi * 4;
#pragma unroll
      for (int j = 0; j < 4; ++j)
        C[(rbase + j) * (size_t)N + col] = acc[mi][ni][j];
    }
  }
}

// ---------- fallback: f32 tiled GEMM (only if ws_size too small) ----------
__global__ __launch_bounds__(256) void gemm_f32_fallback(const float* __restrict__ X,
                                                         const float* __restrict__ Km,
                                                         float* __restrict__ C,
                                                         int M, int N, int K) {
  __shared__ float As[64][16];
  __shared__ float Bs[16][65];
  const int nBN = N / 64;
  const int bm = blockIdx.x / nBN;
  const int bn = blockIdx.x % nBN;
  const int t = threadIdx.x;
  const int tx = t & 15, ty = t >> 4;
  float acc[4][4] = {};
  for (int kb = 0; kb < K; kb += 16) {
#pragma unroll
    for (int i = 0; i < 4; ++i) {
      int e = t + i * 256;
      int r = e >> 4, c = e & 15;
      As[r][c] = X[(size_t)(bm * 64 + r) * K + kb + c];
      int rk = e >> 6, cn = e & 63;
      float v = Km[(size_t)(kb + rk) * N + bn * 64 + cn];
      Bs[rk][cn] = (v >= 0.f) ? 1.f : -1.f;
    }
    __syncthreads();
#pragma unroll
    for (int kk = 0; kk < 16; ++kk) {
      float a[4], b[4];
#pragma unroll
      for (int r = 0; r < 4; ++r) a[r] = As[ty * 4 + r][kk];
#pragma unroll
      for (int c = 0; c < 4; ++c) b[c] = Bs[kk][tx * 4 + c];
#pragma unroll
      for (int r = 0; r < 4; ++r)
#pragma unroll
        for (int c = 0; c < 4; ++c) acc[r][c] += a[r] * b[c];
    }
    __syncthreads();
  }
#pragma unroll
  for (int r = 0; r < 4; ++r)
#pragma unroll
    for (int c = 0; c < 4; ++c)
      C[(size_t)(bm * 64 + ty * 4 + r) * N + bn * 64 + tx * 4 + c] = acc[r][c];
}

extern "C" void kernel_launch(void* const* d_in, const int* in_sizes, int n_in,
                              void* d_out, int out_size, void* d_ws, size_t ws_size,
                              hipStream_t stream) {
  const float* x = (const float*)d_in[0];
  const float* kern = (const float*)d_in[1];
  float* out = (float*)d_out;

  const int K = 4096;             // D_IN
  const int N = 4096;             // UNITS
  const int M = in_sizes[0] / K;  // 8192

  const size_t a_bytes = (size_t)M * K * 2;
  const size_t b_bytes = (size_t)N * K * 2;

  if (ws_size >= a_bytes + b_bytes && (M % 256) == 0 && (N % 256) == 0 && (K % 128) == 0) {
    unsigned short* A = (unsigned short*)d_ws;
    unsigned short* Bt = (unsigned short*)((char*)d_ws + a_bytes);
    convert_x_kernel<<<2048, 256, 0, stream>>>(x, A, (size_t)M * K);
    sign_transpose_kernel<<<dim3(K / 64, N / 64), 256, 0, stream>>>(kern, Bt, K, N);
    gemm_bf16_256<<<(M / 256) * (N / 256), 512, 0, stream>>>(A, Bt, out, M, N, K);
  } else {
    gemm_f32_fallback<<<(M / 64) * (N / 64), 256, 0, stream>>>(x, kern, out, M, N, K);
  }
}